// Round 2
// baseline (1540.928 us; speedup 1.0000x reference)
//
#include <hip/hip_runtime.h>
#include <stdint.h>
#include <stddef.h>

// ---------------------------------------------------------------------------
// MixtralAttention on MI355X (gfx950).
// Inputs fp32 (positions int32), output fp32. Compute in bf16 MFMA + fp32 acc.
// B=2, S=2048, HIDDEN=4096, N_HEADS=32, N_KV=8, HEAD_DIM=128
// Pipeline: QKV GEMM (fp32 in -> bf16 ws) -> RoPE (bf16 in place)
//           -> causal GQA flash attention (bf16 ws) -> O GEMM (-> fp32 out)
// ---------------------------------------------------------------------------

typedef short short8 __attribute__((ext_vector_type(8)));
typedef float f32x4  __attribute__((ext_vector_type(4)));

__device__ __forceinline__ float bf2f(short s) {
    union { uint32_t u; float f; } v;
    v.u = ((uint32_t)(uint16_t)s) << 16;
    return v.f;
}
__device__ __forceinline__ short f2bf(float f) {
    union { float f; uint32_t u; } v;
    v.f = f;
    uint32_t u = v.u;
    uint32_t r = (u + 0x7FFFu + ((u >> 16) & 1u)) >> 16;  // RNE
    return (short)(uint16_t)r;
}

// load 8 consecutive elements as bf16 (convert if fp32 source)
__device__ __forceinline__ short8 ldcvt8(const short* p) {
    return *(const short8*)p;
}
__device__ __forceinline__ short8 ldcvt8(const float* p) {
    float4 a = *(const float4*)p;
    float4 b = *(const float4*)(p + 4);
    short8 r;
    r[0] = f2bf(a.x); r[1] = f2bf(a.y); r[2] = f2bf(a.z); r[3] = f2bf(a.w);
    r[4] = f2bf(b.x); r[5] = f2bf(b.y); r[6] = f2bf(b.z); r[7] = f2bf(b.w);
    return r;
}

__device__ __forceinline__ void st_out(short* p, float v) { *p = f2bf(v); }
__device__ __forceinline__ void st_out(float* p, float v) { *p = v; }

// ---------------------------------------------------------------------------
// GEMM: C[M,N] = A[M,K] @ B[K,N]; AT/BT in {float(bf16-converted), short},
// CT in {float, short}. f32 accumulate via mfma_f32_16x16x32_bf16.
// Block: 256 thr = 4 waves (2x2), tile 128x128, BK=64.
// LDS: As[128][72] row-major; Bs[128][72] = B transposed (Bs[n][k]).
// ---------------------------------------------------------------------------
template <typename AT, typename BT, typename CT>
__global__ __launch_bounds__(256, 2)
void gemm_kernel(const AT* __restrict__ A, const BT* __restrict__ B,
                 CT* __restrict__ C, int M, int N, int K)
{
    __shared__ __align__(16) short As[128][72];
    __shared__ __align__(16) short Bs[128][72];

    const int tid  = threadIdx.x;
    const int lane = tid & 63;
    const int wave = tid >> 6;
    const int l16  = lane & 15;
    const int quad = lane >> 4;
    const int wm   = wave >> 1;
    const int wn   = wave & 1;
    const int mb   = blockIdx.y;
    const int nb   = blockIdx.x;

    const AT* Ab = A + (size_t)mb * 128 * K;
    const BT* Bb = B + (size_t)nb * 128;

    f32x4 acc[4][4];
#pragma unroll
    for (int i = 0; i < 4; i++)
#pragma unroll
        for (int j = 0; j < 4; j++) acc[i][j] = {0.f, 0.f, 0.f, 0.f};

    const int aRow = tid >> 3;          // + 32*j
    const int aCol = (tid & 7) * 8;
    const int bK   = tid & 63;
    const int bN8  = tid >> 6;          // + 4*j

    for (int kb = 0; kb < K; kb += 64) {
        // stage A tile 128x64 (convert to bf16)
#pragma unroll
        for (int j = 0; j < 4; j++) {
            int row = aRow + 32 * j;
            short8 v = ldcvt8(Ab + (size_t)row * K + kb + aCol);
            *(short8*)(&As[row][aCol]) = v;
        }
        // stage B tile 64x128, transposed into Bs[n][k]
#pragma unroll
        for (int j = 0; j < 4; j++) {
            int n = (bN8 + 4 * j) * 8;
            short8 v = ldcvt8(Bb + (size_t)(kb + bK) * N + n);
#pragma unroll
            for (int i = 0; i < 8; i++) Bs[n + i][bK] = v[i];
        }
        __syncthreads();

#pragma unroll
        for (int ks = 0; ks < 2; ks++) {
            short8 af[4], bf[4];
#pragma unroll
            for (int t = 0; t < 4; t++) {
                af[t] = *(const short8*)(&As[wm * 64 + t * 16 + l16][ks * 32 + quad * 8]);
                bf[t] = *(const short8*)(&Bs[wn * 64 + t * 16 + l16][ks * 32 + quad * 8]);
            }
#pragma unroll
            for (int mt = 0; mt < 4; mt++)
#pragma unroll
                for (int nt = 0; nt < 4; nt++)
                    acc[mt][nt] = __builtin_amdgcn_mfma_f32_16x16x32_bf16(
                        af[mt], bf[nt], acc[mt][nt], 0, 0, 0);
        }
        __syncthreads();
    }

    // epilogue: C/D layout row = quad*4+reg, col = lane&15
#pragma unroll
    for (int mt = 0; mt < 4; mt++)
#pragma unroll
        for (int nt = 0; nt < 4; nt++)
#pragma unroll
            for (int r = 0; r < 4; r++) {
                int row = mb * 128 + wm * 64 + mt * 16 + quad * 4 + r;
                int col = nb * 128 + wn * 64 + nt * 16 + l16;
                st_out(&C[(size_t)row * N + col], acc[mt][nt][r]);
            }
}

// ---------------------------------------------------------------------------
// RoPE (neox): rotate q (32 heads) and k (8 heads) in-place in bf16 qkv ws.
// ---------------------------------------------------------------------------
__global__ __launch_bounds__(256)
void rope_kernel(const int* __restrict__ positions, short* __restrict__ qkv)
{
    const int tok = blockIdx.x;
    const float fp = (float)positions[tok];
    short* base = qkv + (size_t)tok * 6144;
    const float c0 = 0.14391156516f;  // ln(10000)/64

    for (int i = threadIdx.x; i < 40 * 64; i += 256) {
        int head = i >> 6, d = i & 63;
        int off = (head < 32) ? head * 128 : 4096 + (head - 32) * 128;
        float inv = expf(-(float)d * c0);
        float ang = fp * inv;
        float c = cosf(ang);
        float s = sinf(ang);
        float x1 = bf2f(base[off + d]);
        float x2 = bf2f(base[off + d + 64]);
        base[off + d]      = f2bf(x1 * c - x2 * s);
        base[off + d + 64] = f2bf(x2 * c + x1 * s);
    }
}

// ---------------------------------------------------------------------------
// Causal GQA flash attention (bf16 ws -> bf16 ws).
// Grid: b(2) x h(32) x qb(32) = 2048 blocks. Block: 4 waves x 16 q-rows.
// ---------------------------------------------------------------------------
__global__ __launch_bounds__(256, 2)
void attn_kernel(const short* __restrict__ qkv, short* __restrict__ outp)
{
    __shared__ __align__(16) short Ks[64][136];
    __shared__ __align__(16) short Vt[128][72];
    __shared__ __align__(16) short Pw[4][16][72];

    const int blk = blockIdx.x;
    const int qb  = blk & 31;
    const int h   = (blk >> 5) & 31;
    const int b   = blk >> 10;
    const int hk  = h >> 2;

    const int tid  = threadIdx.x;
    const int lane = tid & 63;
    const int wave = tid >> 6;
    const int l16  = lane & 15;
    const int quad = lane >> 4;

    const size_t ld = 6144;
    const short* Kbase = qkv + (size_t)b * 2048 * ld + 4096 + hk * 128;
    const short* Vbase = Kbase + 1024;

    // Q fragments: A[m=l16][k = ks*32 + quad*8 + j]
    short8 qf[4];
    {
        const short* Qp = qkv + (size_t)(b * 2048 + qb * 64 + wave * 16 + l16) * ld + h * 128;
#pragma unroll
        for (int ks = 0; ks < 4; ks++)
            qf[ks] = *(const short8*)(Qp + ks * 32 + quad * 8);
    }

    f32x4 oacc[8];
#pragma unroll
    for (int g = 0; g < 8; g++) oacc[g] = {0.f, 0.f, 0.f, 0.f};
    float mrow[4] = {-1e30f, -1e30f, -1e30f, -1e30f};
    float lrow[4] = {0.f, 0.f, 0.f, 0.f};
    const float scale = 0.08838834764831845f;  // 1/sqrt(128)

    const int kRow = tid >> 4;          // + 16*j
    const int kCol = (tid & 15) * 8;
    const int vRow = tid & 63;
    const int vN8  = tid >> 6;          // + 4*j

    for (int kt = 0; kt <= qb; kt++) {
        __syncthreads();
        // stage K tile (row-major)
#pragma unroll
        for (int j = 0; j < 4; j++) {
            int row = kRow + 16 * j;
            short8 v = *(const short8*)(Kbase + (size_t)(kt * 64 + row) * ld + kCol);
            *(short8*)(&Ks[row][kCol]) = v;
        }
        // stage V tile transposed: Vt[d][j]
#pragma unroll
        for (int j = 0; j < 4; j++) {
            int n = (vN8 + 4 * j) * 8;
            short8 v = *(const short8*)(Vbase + (size_t)(kt * 64 + vRow) * ld + n);
#pragma unroll
            for (int i = 0; i < 8; i++) Vt[n + i][vRow] = v[i];
        }
        __syncthreads();

        // S = Q @ K^T for this wave's 16 rows x 64 cols
        f32x4 sacc[4];
#pragma unroll
        for (int g = 0; g < 4; g++) {
            sacc[g] = {0.f, 0.f, 0.f, 0.f};
#pragma unroll
            for (int ks = 0; ks < 4; ks++) {
                short8 kf = *(const short8*)(&Ks[l16 + 16 * g][ks * 32 + quad * 8]);
                sacc[g] = __builtin_amdgcn_mfma_f32_16x16x32_bf16(qf[ks], kf, sacc[g], 0, 0, 0);
            }
        }

        // scale + causal mask + online softmax (each row lives in one quad)
        const int srow_base = qb * 64 + wave * 16 + quad * 4;
        const bool diag = (kt == qb);
        float sv[4][4];
#pragma unroll
        for (int g = 0; g < 4; g++)
#pragma unroll
            for (int r = 0; r < 4; r++) {
                float x = sacc[g][r] * scale;
                if (diag) {
                    int t = kt * 64 + g * 16 + l16;
                    if (t > srow_base + r) x = -1e30f;
                }
                sv[g][r] = x;
            }
#pragma unroll
        for (int r = 0; r < 4; r++) {
            float mx = fmaxf(fmaxf(sv[0][r], sv[1][r]), fmaxf(sv[2][r], sv[3][r]));
#pragma unroll
            for (int off = 1; off < 16; off <<= 1)
                mx = fmaxf(mx, __shfl_xor(mx, off, 64));
            float mn = fmaxf(mrow[r], mx);
            float al = __expf(mrow[r] - mn);
            float rs = 0.f;
#pragma unroll
            for (int g = 0; g < 4; g++) {
                float p = __expf(sv[g][r] - mn);
                sv[g][r] = p;
                rs += p;
            }
#pragma unroll
            for (int off = 1; off < 16; off <<= 1)
                rs += __shfl_xor(rs, off, 64);
            lrow[r] = lrow[r] * al + rs;
            mrow[r] = mn;
#pragma unroll
            for (int gd = 0; gd < 8; gd++) oacc[gd][r] *= al;
        }

        // P: C-layout -> LDS (per-wave region)
#pragma unroll
        for (int g = 0; g < 4; g++)
#pragma unroll
            for (int r = 0; r < 4; r++)
                Pw[wave][quad * 4 + r][l16 + 16 * g] = f2bf(sv[g][r]);
        __syncthreads();

        // O += P @ V
#pragma unroll
        for (int ks = 0; ks < 2; ks++) {
            short8 af = *(const short8*)(&Pw[wave][l16][ks * 32 + quad * 8]);
#pragma unroll
            for (int gd = 0; gd < 8; gd++) {
                short8 vf = *(const short8*)(&Vt[l16 + 16 * gd][ks * 32 + quad * 8]);
                oacc[gd] = __builtin_amdgcn_mfma_f32_16x16x32_bf16(af, vf, oacc[gd], 0, 0, 0);
            }
        }
    }

    // epilogue: normalize by l, write attn output [token][h*128 + d]
    const int srow_base = qb * 64 + wave * 16 + quad * 4;
#pragma unroll
    for (int r = 0; r < 4; r++) {
        float inv = 1.0f / lrow[r];
        size_t rowoff = (size_t)(b * 2048 + srow_base + r) * 4096 + h * 128;
#pragma unroll
        for (int gd = 0; gd < 8; gd++)
            outp[rowoff + gd * 16 + l16] = f2bf(oacc[gd][r] * inv);
    }
}

// ---------------------------------------------------------------------------
// launcher
// ---------------------------------------------------------------------------
extern "C" void kernel_launch(void* const* d_in, const int* in_sizes, int n_in,
                              void* d_out, int out_size, void* d_ws, size_t ws_size,
                              hipStream_t stream)
{
    const int*   positions = (const int*)d_in[0];
    const float* hidden    = (const float*)d_in[1];  // fp32 [4096, 4096]
    const float* w_qkv     = (const float*)d_in[2];  // fp32 [4096, 6144]
    const float* w_o       = (const float*)d_in[3];  // fp32 [4096, 4096]
    float* out = (float*)d_out;                      // fp32 [4096, 4096]

    short* qkv  = (short*)d_ws;                      // bf16 [4096, 6144]
    short* attn = qkv + (size_t)4096 * 6144;         // bf16 [4096, 4096]

    // 1) QKV projection (fp32 inputs -> bf16 ws)
    gemm_kernel<float, float, short><<<dim3(48, 32), 256, 0, stream>>>(
        hidden, w_qkv, qkv, 4096, 6144, 4096);
    // 2) RoPE in place on q,k
    rope_kernel<<<4096, 256, 0, stream>>>(positions, qkv);
    // 3) causal GQA flash attention
    attn_kernel<<<2048, 256, 0, stream>>>(qkv, attn);
    // 4) output projection (bf16 ws x fp32 weights -> fp32 out)
    gemm_kernel<short, float, float><<<dim3(32, 32), 256, 0, stream>>>(
        attn, w_o, out, 4096, 4096, 4096);
}

// Round 3
// 1161.866 us; speedup vs baseline: 1.3263x; 1.3263x over previous
//
#include <hip/hip_runtime.h>
#include <stdint.h>
#include <stddef.h>

// ---------------------------------------------------------------------------
// MixtralAttention on MI355X (gfx950).
// fp32 in/out, bf16 MFMA compute. B=2,S=2048,H=4096,NH=32,NKV=8,D=128
// qkv ws: [4096][6144] bf16 (48MB) ; wT ws: 32MB (reused 3x, stream-ordered)
// Attention output written in-place into the q-slot of qkv.
// ---------------------------------------------------------------------------

typedef short short8 __attribute__((ext_vector_type(8)));
typedef float f32x4  __attribute__((ext_vector_type(4)));

__device__ __forceinline__ float bf2f(short s) {
    union { uint32_t u; float f; } v;
    v.u = ((uint32_t)(uint16_t)s) << 16;
    return v.f;
}
__device__ __forceinline__ short f2bf(float f) {
    union { float f; uint32_t u; } v;
    v.f = f;
    uint32_t u = v.u;
    uint32_t r = (u + 0x7FFFu + ((u >> 16) & 1u)) >> 16;  // RNE
    return (short)(uint16_t)r;
}
__device__ __forceinline__ short8 ldcvt8(const float* p) {
    float4 a = *(const float4*)p;
    float4 b = *(const float4*)(p + 4);
    short8 r;
    r[0] = f2bf(a.x); r[1] = f2bf(a.y); r[2] = f2bf(a.z); r[3] = f2bf(a.w);
    r[4] = f2bf(b.x); r[5] = f2bf(b.y); r[6] = f2bf(b.z); r[7] = f2bf(b.w);
    return r;
}
__device__ __forceinline__ void st_out(short* p, float v) { *p = f2bf(v); }
__device__ __forceinline__ void st_out(float* p, float v) { *p = v; }

#define GLDS16(g, l) __builtin_amdgcn_global_load_lds( \
    (const __attribute__((address_space(1))) void*)(g), \
    (__attribute__((address_space(3))) void*)(l), 16, 0, 0)

// ---------------------------------------------------------------------------
// Tiled transpose + fp32->bf16 convert: in[R][ldin] (slice width Cs) -> out[Cs][R]
// ---------------------------------------------------------------------------
__global__ __launch_bounds__(256)
void transpose_cvt(const float* __restrict__ in, int ldin,
                   short* __restrict__ out, int R, int Cs)
{
    __shared__ short tile[64][72];
    const int bc = blockIdx.x * 64;   // col base (input)
    const int br = blockIdx.y * 64;   // row base (input)
    const int tid = threadIdx.x;
    const int r  = tid >> 2;          // 0..63
    const int c0 = (tid & 3) * 16;

    const float* src = in + (size_t)(br + r) * ldin + bc + c0;
#pragma unroll
    for (int i = 0; i < 4; i++) {
        float4 v = *(const float4*)(src + 4 * i);
        tile[c0 + 4 * i + 0][r] = f2bf(v.x);
        tile[c0 + 4 * i + 1][r] = f2bf(v.y);
        tile[c0 + 4 * i + 2][r] = f2bf(v.z);
        tile[c0 + 4 * i + 3][r] = f2bf(v.w);
    }
    __syncthreads();

    short* dst = out + (size_t)(bc + r) * R + br + c0;
    *(short8*)(dst)     = *(const short8*)(&tile[r][c0]);
    *(short8*)(dst + 4294967296ull * 0 + 8) = *(const short8*)(&tile[r][c0 + 8]);
}

// ---------------------------------------------------------------------------
// Staging helpers. LDS tile layout: T[128][64] bf16, unpadded, XOR-swizzled:
// element (row, chunk16B c_log) lives at byte row*128 + (c_log ^ (row&7))*16.
// ---------------------------------------------------------------------------
// fp32 source: vector load + convert + ds_write_b128 (per-lane scatter ok)
__device__ __forceinline__ void stage_tile(const float* __restrict__ Ab, size_t lda,
                                           int kb, short* T, int tid)
{
    const int aRow = tid >> 3;        // 0..31 (+32*j)
    const int aChk = tid & 7;
#pragma unroll
    for (int j = 0; j < 4; j++) {
        int row = aRow + 32 * j;
        short8 v = ldcvt8(Ab + (size_t)row * lda + kb + aChk * 8);
        *(short8*)(&T[row * 64 + ((aChk ^ (row & 7)) * 8)]) = v;
    }
}
// bf16 source: global_load_lds width 16 (LDS dest = wave base + lane*16)
__device__ __forceinline__ void stage_tile(const short* __restrict__ Ab, size_t lda,
                                           int kb, short* T, int tid)
{
    const int lane = tid & 63;
    const int wave = tid >> 6;
    const int sRow = lane >> 3;       // 0..7
    const int sPhy = lane & 7;
    const int logc = sPhy ^ sRow;     // (row&7)==sRow for all j
#pragma unroll
    for (int j = 0; j < 4; j++) {
        int row = wave * 32 + j * 8 + sRow;
        const short* g = Ab + (size_t)row * lda + kb + logc * 8;
        GLDS16(g, T + (size_t)(wave * 32 + j * 8) * 64);
    }
}

// ---------------------------------------------------------------------------
// GEMM: C[M,N] = A[M,K] @ Bt[N,K]^T.  A: fp32 (convert) or bf16; Bt bf16
// pre-transposed [N][K]; C fp32 or bf16 with row stride ldc.
// Block 256 = 4 waves (2x2), tile 128x128, BK=64, mfma 16x16x32 bf16.
// ---------------------------------------------------------------------------
template <typename AT, typename CT>
__global__ __launch_bounds__(256, 2)
void gemm_tn(const AT* __restrict__ A, int lda, const short* __restrict__ Bt,
             CT* __restrict__ C, int ldc, int M, int N, int K)
{
    __shared__ __align__(16) short As[128 * 64];
    __shared__ __align__(16) short Bs[128 * 64];

    const int tid  = threadIdx.x;
    const int lane = tid & 63;
    const int wave = tid >> 6;
    const int l16  = lane & 15;
    const int quad = lane >> 4;
    const int wm   = wave >> 1;
    const int wn   = wave & 1;
    const int mb   = blockIdx.y;
    const int nb   = blockIdx.x;

    const AT*    Ab = A  + (size_t)mb * 128 * lda;
    const short* Bb = Bt + (size_t)nb * 128 * K;

    f32x4 acc[4][4];
#pragma unroll
    for (int i = 0; i < 4; i++)
#pragma unroll
        for (int j = 0; j < 4; j++) acc[i][j] = {0.f, 0.f, 0.f, 0.f};

    for (int kb = 0; kb < K; kb += 64) {
        __syncthreads();
        stage_tile(Ab, (size_t)lda, kb, As, tid);
        stage_tile(Bb, (size_t)K,   kb, Bs, tid);
        __syncthreads();

#pragma unroll
        for (int ks = 0; ks < 2; ks++) {
            short8 af[4], bf[4];
#pragma unroll
            for (int t = 0; t < 4; t++) {
                int ar = wm * 64 + t * 16 + l16;
                int br = wn * 64 + t * 16 + l16;
                af[t] = *(const short8*)(&As[ar * 64 + (((ks * 4 + quad) ^ (ar & 7)) * 8)]);
                bf[t] = *(const short8*)(&Bs[br * 64 + (((ks * 4 + quad) ^ (br & 7)) * 8)]);
            }
#pragma unroll
            for (int mt = 0; mt < 4; mt++)
#pragma unroll
                for (int nt = 0; nt < 4; nt++)
                    acc[mt][nt] = __builtin_amdgcn_mfma_f32_16x16x32_bf16(
                        af[mt], bf[nt], acc[mt][nt], 0, 0, 0);
        }
    }

    // epilogue: C/D layout row = quad*4+reg, col = lane&15
#pragma unroll
    for (int mt = 0; mt < 4; mt++)
#pragma unroll
        for (int nt = 0; nt < 4; nt++)
#pragma unroll
            for (int r = 0; r < 4; r++) {
                int row = mb * 128 + wm * 64 + mt * 16 + quad * 4 + r;
                int col = nb * 128 + wn * 64 + nt * 16 + l16;
                st_out(&C[(size_t)row * ldc + col], acc[mt][nt][r]);
            }
}

// ---------------------------------------------------------------------------
// RoPE (neox) in-place on q (32 heads) and k (8 heads) in bf16 qkv ws.
// ---------------------------------------------------------------------------
__global__ __launch_bounds__(256)
void rope_kernel(const int* __restrict__ positions, short* __restrict__ qkv)
{
    const int tok = blockIdx.x;
    const float fp = (float)positions[tok];
    short* base = qkv + (size_t)tok * 6144;
    const float c0 = 0.14391156516f;  // ln(10000)/64

    for (int i = threadIdx.x; i < 40 * 64; i += 256) {
        int head = i >> 6, d = i & 63;
        int off = (head < 32) ? head * 128 : 4096 + (head - 32) * 128;
        float inv = expf(-(float)d * c0);
        float ang = fp * inv;
        float c = cosf(ang);
        float s = sinf(ang);
        float x1 = bf2f(base[off + d]);
        float x2 = bf2f(base[off + d + 64]);
        base[off + d]      = f2bf(x1 * c - x2 * s);
        base[off + d + 64] = f2bf(x2 * c + x1 * s);
    }
}

// ---------------------------------------------------------------------------
// Causal GQA flash attention; output written IN-PLACE into the q-slot.
// Grid: b(2) x h(32) x qb(32) = 2048 blocks. Block: 4 waves x 16 q-rows.
// ---------------------------------------------------------------------------
__global__ __launch_bounds__(256, 2)
void attn_kernel(short* __restrict__ qkv)
{
    __shared__ __align__(16) short Ks[64][136];
    __shared__ __align__(16) short Vt[128][72];
    __shared__ __align__(16) short Pw[4][16][72];

    const int blk = blockIdx.x;
    const int qb  = blk & 31;
    const int h   = (blk >> 5) & 31;
    const int b   = blk >> 10;
    const int hk  = h >> 2;

    const int tid  = threadIdx.x;
    const int lane = tid & 63;
    const int wave = tid >> 6;
    const int l16  = lane & 15;
    const int quad = lane >> 4;

    const size_t ld = 6144;
    const short* Kbase = qkv + (size_t)b * 2048 * ld + 4096 + hk * 128;
    const short* Vbase = Kbase + 1024;

    // Q fragments: A[m=l16][k = ks*32 + quad*8 + j] — fully read before K-loop
    short8 qf[4];
    {
        const short* Qp = qkv + (size_t)(b * 2048 + qb * 64 + wave * 16 + l16) * ld + h * 128;
#pragma unroll
        for (int ks = 0; ks < 4; ks++)
            qf[ks] = *(const short8*)(Qp + ks * 32 + quad * 8);
    }

    f32x4 oacc[8];
#pragma unroll
    for (int g = 0; g < 8; g++) oacc[g] = {0.f, 0.f, 0.f, 0.f};
    float mrow[4] = {-1e30f, -1e30f, -1e30f, -1e30f};
    float lrow[4] = {0.f, 0.f, 0.f, 0.f};
    const float scale = 0.08838834764831845f;  // 1/sqrt(128)

    const int kRow = tid >> 4;          // + 16*j
    const int kCol = (tid & 15) * 8;
    const int vRow = tid & 63;
    const int vN8  = tid >> 6;          // + 4*j

    for (int kt = 0; kt <= qb; kt++) {
        __syncthreads();
#pragma unroll
        for (int j = 0; j < 4; j++) {
            int row = kRow + 16 * j;
            short8 v = *(const short8*)(Kbase + (size_t)(kt * 64 + row) * ld + kCol);
            *(short8*)(&Ks[row][kCol]) = v;
        }
#pragma unroll
        for (int j = 0; j < 4; j++) {
            int n = (vN8 + 4 * j) * 8;
            short8 v = *(const short8*)(Vbase + (size_t)(kt * 64 + vRow) * ld + n);
#pragma unroll
            for (int i = 0; i < 8; i++) Vt[n + i][vRow] = v[i];
        }
        __syncthreads();

        f32x4 sacc[4];
#pragma unroll
        for (int g = 0; g < 4; g++) {
            sacc[g] = {0.f, 0.f, 0.f, 0.f};
#pragma unroll
            for (int ks = 0; ks < 4; ks++) {
                short8 kf = *(const short8*)(&Ks[l16 + 16 * g][ks * 32 + quad * 8]);
                sacc[g] = __builtin_amdgcn_mfma_f32_16x16x32_bf16(qf[ks], kf, sacc[g], 0, 0, 0);
            }
        }

        const int srow_base = qb * 64 + wave * 16 + quad * 4;
        const bool diag = (kt == qb);
        float sv[4][4];
#pragma unroll
        for (int g = 0; g < 4; g++)
#pragma unroll
            for (int r = 0; r < 4; r++) {
                float x = sacc[g][r] * scale;
                if (diag) {
                    int t = kt * 64 + g * 16 + l16;
                    if (t > srow_base + r) x = -1e30f;
                }
                sv[g][r] = x;
            }
#pragma unroll
        for (int r = 0; r < 4; r++) {
            float mx = fmaxf(fmaxf(sv[0][r], sv[1][r]), fmaxf(sv[2][r], sv[3][r]));
#pragma unroll
            for (int off = 1; off < 16; off <<= 1)
                mx = fmaxf(mx, __shfl_xor(mx, off, 64));
            float mn = fmaxf(mrow[r], mx);
            float al = __expf(mrow[r] - mn);
            float rs = 0.f;
#pragma unroll
            for (int g = 0; g < 4; g++) {
                float p = __expf(sv[g][r] - mn);
                sv[g][r] = p;
                rs += p;
            }
#pragma unroll
            for (int off = 1; off < 16; off <<= 1)
                rs += __shfl_xor(rs, off, 64);
            lrow[r] = lrow[r] * al + rs;
            mrow[r] = mn;
#pragma unroll
            for (int gd = 0; gd < 8; gd++) oacc[gd][r] *= al;
        }

#pragma unroll
        for (int g = 0; g < 4; g++)
#pragma unroll
            for (int r = 0; r < 4; r++)
                Pw[wave][quad * 4 + r][l16 + 16 * g] = f2bf(sv[g][r]);
        __syncthreads();

#pragma unroll
        for (int ks = 0; ks < 2; ks++) {
            short8 af = *(const short8*)(&Pw[wave][l16][ks * 32 + quad * 8]);
#pragma unroll
            for (int gd = 0; gd < 8; gd++) {
                short8 vf = *(const short8*)(&Vt[l16 + 16 * gd][ks * 32 + quad * 8]);
                oacc[gd] = __builtin_amdgcn_mfma_f32_16x16x32_bf16(af, vf, oacc[gd], 0, 0, 0);
            }
        }
    }

    // epilogue: write O in-place into the q-slot (ld 6144)
    const int srow_base = qb * 64 + wave * 16 + quad * 4;
#pragma unroll
    for (int r = 0; r < 4; r++) {
        float inv = 1.0f / lrow[r];
        size_t rowoff = (size_t)(b * 2048 + srow_base + r) * ld + h * 128;
#pragma unroll
        for (int gd = 0; gd < 8; gd++)
            qkv[rowoff + gd * 16 + l16] = f2bf(oacc[gd][r] * inv);
    }
}

// ---------------------------------------------------------------------------
// launcher
// ---------------------------------------------------------------------------
extern "C" void kernel_launch(void* const* d_in, const int* in_sizes, int n_in,
                              void* d_out, int out_size, void* d_ws, size_t ws_size,
                              hipStream_t stream)
{
    const int*   positions = (const int*)d_in[0];
    const float* hidden    = (const float*)d_in[1];  // fp32 [4096, 4096]
    const float* w_qkv     = (const float*)d_in[2];  // fp32 [4096, 6144]
    const float* w_o       = (const float*)d_in[3];  // fp32 [4096, 4096]
    float* out = (float*)d_out;                      // fp32 [4096, 4096]

    short* qkv = (short*)d_ws;                       // bf16 [4096][6144], 48 MB
    short* wT  = qkv + (size_t)4096 * 6144;          // 32 MB transpose buffer

    // 1) QKV projection in two N-chunks of 3072 (wT reused, stream-ordered)
    for (int c = 0; c < 2; c++) {
        transpose_cvt<<<dim3(48, 64), 256, 0, stream>>>(
            w_qkv + c * 3072, 6144, wT, 4096, 3072);
        gemm_tn<float, short><<<dim3(24, 32), 256, 0, stream>>>(
            hidden, 4096, wT, qkv + c * 3072, 6144, 4096, 3072, 4096);
    }
    // 2) RoPE in place on q,k
    rope_kernel<<<4096, 256, 0, stream>>>(positions, qkv);
    // 3) causal GQA flash attention (output -> q-slot)
    attn_kernel<<<2048, 256, 0, stream>>>(qkv);
    // 4) output projection: A = q-slot of qkv (lda 6144), B = w_o^T
    transpose_cvt<<<dim3(64, 64), 256, 0, stream>>>(w_o, 4096, wT, 4096, 4096);
    gemm_tn<short, float><<<dim3(32, 32), 256, 0, stream>>>(
        qkv, 6144, wT, out, 4096, 4096, 4096, 4096);
}